// Round 1
// baseline (212.212 us; speedup 1.0000x reference)
//
#include <hip/hip_runtime.h>

typedef __attribute__((ext_vector_type(4))) float f32x4;
typedef __attribute__((ext_vector_type(8))) __bf16 bf16x8;
typedef __attribute__((ext_vector_type(4))) unsigned int ui4;
typedef __attribute__((ext_vector_type(4))) unsigned short us4;
typedef __attribute__((ext_vector_type(8))) unsigned short us8;

#define B_  16
#define C_  512
#define N_  1024
#define G_  32
#define GS  16

__device__ inline unsigned short f2bf(float f) {
  unsigned u = __builtin_bit_cast(unsigned, f);
  u += 0x7fffu + ((u >> 16) & 1u);
  return (unsigned short)(u >> 16);
}

// ---------------- GroupNorm ----------------
__global__ __launch_bounds__(256) void gn_stats(const float* __restrict__ x,
                                                float* __restrict__ stats) {
  int bg = blockIdx.x;                       // b*32+g
  const float* xp = x + (long)bg * (GS * N_);
  int tid = threadIdx.x;
  float s = 0.f, ss = 0.f;
  for (int i = tid; i < GS * N_; i += 256) { float v = xp[i]; s += v; ss += v * v; }
  __shared__ float r1[256], r2[256];
  r1[tid] = s; r2[tid] = ss; __syncthreads();
  for (int off = 128; off > 0; off >>= 1) {
    if (tid < off) { r1[tid] += r1[tid + off]; r2[tid] += r2[tid + off]; }
    __syncthreads();
  }
  if (tid == 0) {
    float mean = r1[0] * (1.f / (GS * N_));
    float var  = r2[0] * (1.f / (GS * N_)) - mean * mean;
    stats[bg * 2]     = mean;
    stats[bg * 2 + 1] = rsqrtf(var + 1e-6f);
  }
}

// normalize + transpose: x[b,c,n] -> ht[(b*N+n)*C + c]  (bf16)
__global__ __launch_bounds__(256) void gn_apply(const float* __restrict__ x,
                                                const float* __restrict__ stats,
                                                const float* __restrict__ gamma,
                                                const float* __restrict__ beta,
                                                unsigned short* __restrict__ ht) {
  int b = blockIdx.z, ct = blockIdx.y, nt = blockIdx.x;
  int c0 = ct * 64, n0 = nt * 64;
  int tid = threadIdx.x;
  __shared__ unsigned short L[64 * 68];
  const float* xp = x + ((long)b * C_ + c0) * N_ + n0;
#pragma unroll
  for (int i = 0; i < 4; ++i) {
    int li = tid + i * 256;        // 0..1023
    int row = li >> 4;             // c offset 0..63
    int col4 = (li & 15) * 4;      // n offset
    f32x4 v = *(const f32x4*)&xp[(long)row * N_ + col4];
    int c = c0 + row;
    float mean = stats[(b * G_ + (c >> 4)) * 2];
    float rstd = stats[(b * G_ + (c >> 4)) * 2 + 1];
    float gm = gamma[c] * rstd;
    float bt = beta[c] - mean * gm;
    us4 o;
    o.x = f2bf(v.x * gm + bt); o.y = f2bf(v.y * gm + bt);
    o.z = f2bf(v.z * gm + bt); o.w = f2bf(v.w * gm + bt);
    *(us4*)&L[row * 68 + col4] = o;
  }
  __syncthreads();
#pragma unroll
  for (int i = 0; i < 2; ++i) {
    int s = tid + i * 256;         // 0..511
    int n = s >> 3;
    int cs = (s & 7) * 8;
    us8 o;
#pragma unroll
    for (int j = 0; j < 8; ++j) o[j] = L[(cs + j) * 68 + n];
    *(us8*)&ht[((long)b * N_ + n0 + n) * C_ + c0 + cs] = o;
  }
}

// ---------------- weight conversion ----------------
__global__ __launch_bounds__(256) void convert_w(const float* __restrict__ wq, const float* __restrict__ wk,
                                                 const float* __restrict__ wv, const float* __restrict__ wo,
                                                 const float* __restrict__ bq, const float* __restrict__ bk,
                                                 unsigned short* __restrict__ wqk, unsigned short* __restrict__ wvb,
                                                 unsigned short* __restrict__ wob, float* __restrict__ bqk) {
  int i = blockIdx.x * 256 + threadIdx.x;
  if (i < C_ * C_) {
    wqk[i]           = f2bf(wq[i]);
    wqk[C_ * C_ + i] = f2bf(wk[i]);
    wvb[i]           = f2bf(wv[i]);
    wob[i]           = f2bf(wo[i]);
  }
  if (i < C_) { bqk[i] = bq[i]; bqk[C_ + i] = bk[i]; }
}

// ---------------- softmax (in-place fp32 row -> bf16 in first half) ----------------
__global__ __launch_bounds__(256) void softmax_rows(float* __restrict__ S) {
  long row = blockIdx.x;
  float* p = S + row * N_;
  int tid = threadIdx.x;
  f32x4 v = *((const f32x4*)p + tid);
  float mx = fmaxf(fmaxf(v.x, v.y), fmaxf(v.z, v.w));
  __shared__ float r[256];
  r[tid] = mx; __syncthreads();
  for (int off = 128; off > 0; off >>= 1) {
    if (tid < off) r[tid] = fmaxf(r[tid], r[tid + off]);
    __syncthreads();
  }
  float M = r[0];
  __syncthreads();
  f32x4 e;
  e.x = __expf(v.x - M); e.y = __expf(v.y - M);
  e.z = __expf(v.z - M); e.w = __expf(v.w - M);
  float sm = e.x + e.y + e.z + e.w;
  r[tid] = sm; __syncthreads();
  for (int off = 128; off > 0; off >>= 1) {
    if (tid < off) r[tid] += r[tid + off];
    __syncthreads();
  }
  float inv = 1.f / r[0];
  us4 o;
  o.x = f2bf(e.x * inv); o.y = f2bf(e.y * inv);
  o.z = f2bf(e.z * inv); o.w = f2bf(e.w * inv);
  *((us4*)p + tid) = o;
}

// ---------------- generic MFMA GEMM:  D[i,j] = sum_k A[i,k]*B[j,k] ----------------
__device__ inline f32x4 mfma16(bf16x8 a, bf16x8 b, f32x4 c) {
  return __builtin_amdgcn_mfma_f32_16x16x32_bf16(a, b, c, 0, 0, 0);
}

// EPI: 0 = +bias[col], bf16 store   1 = +bias[row], bf16 store
//      2 = *scale, f32 store        3 = plain bf16 store
//      4 = +bias[col] + residual, transposed f32 store to [b, col, n]
template<int EPI>
__global__ __launch_bounds__(256) void gemm_k(
    const unsigned short* __restrict__ A, long lda, long Az,
    const unsigned short* __restrict__ Bm, long ldb, long Bz,
    void* __restrict__ Dp, long ldd, long Dz,
    const float* __restrict__ bias, float scale, int K,
    const float* __restrict__ residual) {
  const int z = blockIdx.z;
  const unsigned short* Ab = A + (long)z * Az;
  const unsigned short* Bb = Bm + (long)z * Bz;
  const long row0 = (long)blockIdx.x * 128;
  const long col0 = (long)blockIdx.y * 128;
  const int tid  = threadIdx.x;
  const int lane = tid & 63;
  const int wave = tid >> 6;
  const int wr = (wave >> 1) * 64;
  const int wc = (wave & 1) * 64;
  const int lr = lane & 15;
  const int kh = (lane >> 4) * 8;

  __shared__ unsigned short As[128 * 40];
  __shared__ unsigned short Bs[128 * 40];

  f32x4 acc[4][4];
#pragma unroll
  for (int m = 0; m < 4; ++m)
#pragma unroll
    for (int n = 0; n < 4; ++n) acc[m][n] = f32x4{0.f, 0.f, 0.f, 0.f};

  for (int k0 = 0; k0 < K; k0 += 32) {
    __syncthreads();
#pragma unroll
    for (int s = 0; s < 2; ++s) {
      int seg = tid + s * 256;     // 0..511
      int rr = seg >> 2;           // 0..127
      int ks = (seg & 3) * 8;
      *(ui4*)&As[rr * 40 + ks] = *(const ui4*)&Ab[(row0 + rr) * lda + k0 + ks];
      *(ui4*)&Bs[rr * 40 + ks] = *(const ui4*)&Bb[(col0 + rr) * ldb + k0 + ks];
    }
    __syncthreads();
    bf16x8 af[4], bfr[4];
#pragma unroll
    for (int m = 0; m < 4; ++m) af[m]  = *(const bf16x8*)&As[(wr + m * 16 + lr) * 40 + kh];
#pragma unroll
    for (int n = 0; n < 4; ++n) bfr[n] = *(const bf16x8*)&Bs[(wc + n * 16 + lr) * 40 + kh];
#pragma unroll
    for (int m = 0; m < 4; ++m)
#pragma unroll
      for (int n = 0; n < 4; ++n)
        acc[m][n] = mfma16(af[m], bfr[n], acc[m][n]);
  }

  const int rb = (lane >> 4) * 4;
#pragma unroll
  for (int m = 0; m < 4; ++m) {
#pragma unroll
    for (int n = 0; n < 4; ++n) {
#pragma unroll
      for (int r = 0; r < 4; ++r) {
        long gr = row0 + wr + m * 16 + rb + r;
        long gc = col0 + wc + n * 16 + lr;
        float v = acc[m][n][r];
        if constexpr (EPI == 0) {
          v += bias[gc];
          ((unsigned short*)Dp)[(long)z * Dz + gr * ldd + gc] = f2bf(v);
        } else if constexpr (EPI == 1) {
          v += bias[gr];
          ((unsigned short*)Dp)[(long)z * Dz + gr * ldd + gc] = f2bf(v);
        } else if constexpr (EPI == 2) {
          ((float*)Dp)[(long)z * Dz + gr * ldd + gc] = v * scale;
        } else if constexpr (EPI == 3) {
          ((unsigned short*)Dp)[(long)z * Dz + gr * ldd + gc] = f2bf(v);
        } else {
          v += bias[gc];
          long b  = gr >> 10;
          long nn = gr & 1023;
          long o  = b * (512L * 1024L) + gc * 1024L + nn;
          ((float*)Dp)[o] = v + residual[o];
        }
      }
    }
  }
}

extern "C" void kernel_launch(void* const* d_in, const int* in_sizes, int n_in,
                              void* d_out, int out_size, void* d_ws, size_t ws_size,
                              hipStream_t stream) {
  const float* x     = (const float*)d_in[0];
  const float* gamma = (const float*)d_in[1];
  const float* beta  = (const float*)d_in[2];
  const float* wq    = (const float*)d_in[3];
  const float* bq    = (const float*)d_in[4];
  const float* wk    = (const float*)d_in[5];
  const float* bk    = (const float*)d_in[6];
  const float* wv    = (const float*)d_in[7];
  const float* bv    = (const float*)d_in[8];
  const float* wo    = (const float*)d_in[9];
  const float* bo    = (const float*)d_in[10];
  float* out = (float*)d_out;

  char* ws = (char*)d_ws;
  unsigned short* ht   = (unsigned short*)(ws + 0);           // [16384,512] bf16
  unsigned short* qkt  = (unsigned short*)(ws + 16777216);    // [16384,1024] bf16 (q | k)
  unsigned short* vv   = (unsigned short*)(ws + 50331648);    // [512,16384] bf16
  unsigned short* ot   = (unsigned short*)(ws + 67108864);    // [16384,512] bf16
  float* S             = (float*)(ws + 83886080);             // [16,1024,1024] f32 (P bf16 in-place)
  unsigned short* wqkb = (unsigned short*)(ws + 150994944);   // [1024,512] bf16
  unsigned short* wvb  = (unsigned short*)(ws + 152043520);   // [512,512] bf16
  unsigned short* wob  = (unsigned short*)(ws + 152567808);   // [512,512] bf16
  float* bqk           = (float*)(ws + 153092096);            // [1024] f32
  float* stats         = (float*)(ws + 153096192);            // [512,2] f32

  convert_w<<<1024, 256, 0, stream>>>(wq, wk, wv, wo, bq, bk, wqkb, wvb, wob, bqk);
  gn_stats<<<512, 256, 0, stream>>>(x, stats);
  gn_apply<<<dim3(16, 8, 16), 256, 0, stream>>>(x, stats, gamma, beta, ht);

  // G1: qkt[i, j] = sum_c ht[i,c] * wqk[j,c] + bqk[j]
  gemm_k<0><<<dim3(128, 8, 1), 256, 0, stream>>>(ht, 512, 0, wqkb, 512, 0,
                                                 qkt, 1024, 0, bqk, 0.f, 512, nullptr);
  // G2: vv[c, t] = sum_k wv[c,k] * ht[t,k] + bv[c]
  gemm_k<1><<<dim3(4, 128, 1), 256, 0, stream>>>(wvb, 512, 0, ht, 512, 0,
                                                 vv, 16384, 0, bv, 0.f, 512, nullptr);
  // G3: S[b,i,j] = scale * sum_c q[i,c] * k[j,c]
  gemm_k<2><<<dim3(8, 8, 16), 256, 0, stream>>>(qkt, 1024, 1048576L, qkt + 512, 1024, 1048576L,
                                                S, 1024, 1048576L, nullptr,
                                                0.044194173824159216f, 512, nullptr);
  softmax_rows<<<16384, 256, 0, stream>>>(S);
  // G4: ot[b*N+i, c] = sum_j P[b,i,j] * vv[c, b*N+j]
  gemm_k<3><<<dim3(8, 4, 16), 256, 0, stream>>>((const unsigned short*)S, 2048, 2097152L,
                                                vv, 16384, 1024,
                                                ot, 512, 524288L, nullptr, 0.f, 1024, nullptr);
  // G5: out[b,o,n] = residual + bo[o] + sum_c ot[b*N+n, c] * wo[o,c]
  gemm_k<4><<<dim3(128, 4, 1), 256, 0, stream>>>(ot, 512, 0, wob, 512, 0,
                                                 out, 0, 0, bo, 0.f, 512, x);
}

// Round 2
// 188.329 us; speedup vs baseline: 1.1268x; 1.1268x over previous
//
#include <hip/hip_runtime.h>

typedef __attribute__((ext_vector_type(4))) float f32x4;
typedef __attribute__((ext_vector_type(8))) __bf16 bf16x8;
typedef __attribute__((ext_vector_type(4))) unsigned short us4;
typedef __attribute__((ext_vector_type(8))) unsigned short us8;

#define B_  16
#define C_  512
#define N_  1024
#define G_  32
#define GS  16

__device__ inline unsigned short f2bf(float f) {
  unsigned u = __builtin_bit_cast(unsigned, f);
  u += 0x7fffu + ((u >> 16) & 1u);
  return (unsigned short)(u >> 16);
}
__device__ inline float bf2f(unsigned short u) {
  unsigned x = (unsigned)u << 16;
  return __builtin_bit_cast(float, x);
}

#define GLOAD_LDS16(gp, lp) __builtin_amdgcn_global_load_lds( \
    (const __attribute__((address_space(1))) unsigned int*)(gp), \
    (__attribute__((address_space(3))) unsigned int*)(lp), 16, 0, 0)

// ---------------- GroupNorm ----------------
__global__ __launch_bounds__(256) void gn_stats(const float* __restrict__ x,
                                                float* __restrict__ stats) {
  int bg = blockIdx.x;                       // b*32+g
  const float* xp = x + (long)bg * (GS * N_);
  int tid = threadIdx.x;
  float s = 0.f, ss = 0.f;
  for (int i = tid * 4; i < GS * N_; i += 1024) {
    f32x4 v = *(const f32x4*)&xp[i];
    s += v.x + v.y + v.z + v.w;
    ss += v.x * v.x + v.y * v.y + v.z * v.z + v.w * v.w;
  }
  __shared__ float r1[256], r2[256];
  r1[tid] = s; r2[tid] = ss; __syncthreads();
  for (int off = 128; off > 0; off >>= 1) {
    if (tid < off) { r1[tid] += r1[tid + off]; r2[tid] += r2[tid + off]; }
    __syncthreads();
  }
  if (tid == 0) {
    float mean = r1[0] * (1.f / (GS * N_));
    float var  = r2[0] * (1.f / (GS * N_)) - mean * mean;
    stats[bg * 2]     = mean;
    stats[bg * 2 + 1] = rsqrtf(var + 1e-6f);
  }
}

// normalize + transpose: x[b,c,n] -> ht[(b*N+n)*C + c]  (bf16)
__global__ __launch_bounds__(256) void gn_apply(const float* __restrict__ x,
                                                const float* __restrict__ stats,
                                                const float* __restrict__ gamma,
                                                const float* __restrict__ beta,
                                                unsigned short* __restrict__ ht) {
  int b = blockIdx.z, ct = blockIdx.y, nt = blockIdx.x;
  int c0 = ct * 64, n0 = nt * 64;
  int tid = threadIdx.x;
  __shared__ unsigned short L[64 * 68];
  const float* xp = x + ((long)b * C_ + c0) * N_ + n0;
#pragma unroll
  for (int i = 0; i < 4; ++i) {
    int li = tid + i * 256;        // 0..1023
    int row = li >> 4;             // c offset 0..63
    int col4 = (li & 15) * 4;      // n offset
    f32x4 v = *(const f32x4*)&xp[(long)row * N_ + col4];
    int c = c0 + row;
    float mean = stats[(b * G_ + (c >> 4)) * 2];
    float rstd = stats[(b * G_ + (c >> 4)) * 2 + 1];
    float gm = gamma[c] * rstd;
    float bt = beta[c] - mean * gm;
    us4 o;
    o.x = f2bf(v.x * gm + bt); o.y = f2bf(v.y * gm + bt);
    o.z = f2bf(v.z * gm + bt); o.w = f2bf(v.w * gm + bt);
    *(us4*)&L[row * 68 + col4] = o;
  }
  __syncthreads();
#pragma unroll
  for (int i = 0; i < 2; ++i) {
    int s = tid + i * 256;         // 0..511
    int n = s >> 3;
    int cs = (s & 7) * 8;
    us8 o;
#pragma unroll
    for (int j = 0; j < 8; ++j) o[j] = L[(cs + j) * 68 + n];
    *(us8*)&ht[((long)b * N_ + n0 + n) * C_ + c0 + cs] = o;
  }
}

// ---------------- weight conversion ----------------
__global__ __launch_bounds__(256) void convert_w(const float* __restrict__ wq, const float* __restrict__ wk,
                                                 const float* __restrict__ wv, const float* __restrict__ wo,
                                                 const float* __restrict__ bq, const float* __restrict__ bk,
                                                 unsigned short* __restrict__ wqk, unsigned short* __restrict__ wvb,
                                                 unsigned short* __restrict__ wob, float* __restrict__ bqk) {
  int i = blockIdx.x * 256 + threadIdx.x;
  if (i < C_ * C_) {
    wqk[i]           = f2bf(wq[i]);
    wqk[C_ * C_ + i] = f2bf(wk[i]);
    wvb[i]           = f2bf(wv[i]);
    wob[i]           = f2bf(wo[i]);
  }
  if (i < C_) { bqk[i] = bq[i]; bqk[C_ + i] = bk[i]; }
}

// ---------------- softmax (bf16 row in-place) ----------------
__global__ __launch_bounds__(256) void softmax_rows(unsigned short* __restrict__ S) {
  long row = blockIdx.x;
  unsigned short* p = S + row * N_;
  int tid = threadIdx.x;
  us4 v = *((const us4*)p + tid);
  float f0 = bf2f(v.x), f1 = bf2f(v.y), f2 = bf2f(v.z), f3 = bf2f(v.w);
  float mx = fmaxf(fmaxf(f0, f1), fmaxf(f2, f3));
  __shared__ float r[256];
  r[tid] = mx; __syncthreads();
  for (int off = 128; off > 0; off >>= 1) {
    if (tid < off) r[tid] = fmaxf(r[tid], r[tid + off]);
    __syncthreads();
  }
  float M = r[0];
  __syncthreads();
  float e0 = __expf(f0 - M), e1 = __expf(f1 - M), e2 = __expf(f2 - M), e3 = __expf(f3 - M);
  r[tid] = e0 + e1 + e2 + e3; __syncthreads();
  for (int off = 128; off > 0; off >>= 1) {
    if (tid < off) r[tid] += r[tid + off];
    __syncthreads();
  }
  float inv = 1.f / r[0];
  us4 o;
  o.x = f2bf(e0 * inv); o.y = f2bf(e1 * inv);
  o.z = f2bf(e2 * inv); o.w = f2bf(e3 * inv);
  *((us4*)p + tid) = o;
}

// ---------------- MFMA GEMM (m97 structure):  D[i,j] = sum_k A[i,k]*B[j,k] ----------------
__device__ inline f32x4 mfma16(bf16x8 a, bf16x8 b, f32x4 c) {
  return __builtin_amdgcn_mfma_f32_16x16x32_bf16(a, b, c, 0, 0, 0);
}

// EPI: 0 = +bias[col], bf16 store      1 = +bias[row], bf16 store
//      2 = *scale, bf16 store          3 = plain bf16 store
//      4 = +bias[row] + residual, fp32 store to out[z, row, col]
template<int EPI>
__global__ __launch_bounds__(256) void gemm_k(
    const unsigned short* __restrict__ A, long lda, long Az,
    const unsigned short* __restrict__ Bm, long ldb, long Bz,
    void* __restrict__ Dp, long ldd, long Dz,
    const float* __restrict__ bias, float scale, int K,
    const float* __restrict__ residual) {
  const int z = blockIdx.z;
  const long row0 = (long)blockIdx.x * 128;
  const long col0 = (long)blockIdx.y * 128;
  const int tid  = threadIdx.x;
  const int lane = tid & 63;
  const int wave = tid >> 6;
  const int wr = (wave >> 1) * 64;
  const int wc = (wave & 1) * 64;
  const int lr = lane & 15;
  const int kh = (lane >> 4) * 8;

  __shared__ unsigned short As[128 * 32];
  __shared__ unsigned short Bs[128 * 32];

  // staging coords: seg = wave*2 + s covers LDS rows seg*16..seg*16+15
  const int sr  = (lane >> 2);        // row within 16-row segment
  const int sk  = (lane & 3) * 8;     // k offset (shorts)
  const unsigned short* ga0 = A  + (long)z * Az + (row0 + wave * 32 + sr) * lda + sk;
  const unsigned short* gb0 = Bm + (long)z * Bz + (col0 + wave * 32 + sr) * ldb + sk;

  f32x4 acc[4][4];
#pragma unroll
  for (int m = 0; m < 4; ++m)
#pragma unroll
    for (int n = 0; n < 4; ++n) acc[m][n] = f32x4{0.f, 0.f, 0.f, 0.f};

  for (int k0 = 0; k0 < K; k0 += 32) {
    __syncthreads();
#pragma unroll
    for (int s = 0; s < 2; ++s) {
      GLOAD_LDS16(ga0 + (long)s * 16 * lda + k0, &As[(wave * 2 + s) * 512]);
      GLOAD_LDS16(gb0 + (long)s * 16 * ldb + k0, &Bs[(wave * 2 + s) * 512]);
    }
    __syncthreads();
    bf16x8 af[4], bfr[4];
#pragma unroll
    for (int m = 0; m < 4; ++m) af[m]  = *(const bf16x8*)&As[(wr + m * 16 + lr) * 32 + kh];
#pragma unroll
    for (int n = 0; n < 4; ++n) bfr[n] = *(const bf16x8*)&Bs[(wc + n * 16 + lr) * 32 + kh];
#pragma unroll
    for (int m = 0; m < 4; ++m)
#pragma unroll
      for (int n = 0; n < 4; ++n)
        acc[m][n] = mfma16(af[m], bfr[n], acc[m][n]);
  }

  const int rb = (lane >> 4) * 4;
#pragma unroll
  for (int m = 0; m < 4; ++m) {
#pragma unroll
    for (int n = 0; n < 4; ++n) {
#pragma unroll
      for (int r = 0; r < 4; ++r) {
        long gr = row0 + wr + m * 16 + rb + r;
        long gc = col0 + wc + n * 16 + lr;
        float v = acc[m][n][r];
        if constexpr (EPI == 0) {
          v += bias[gc];
          ((unsigned short*)Dp)[(long)z * Dz + gr * ldd + gc] = f2bf(v);
        } else if constexpr (EPI == 1) {
          v += bias[gr];
          ((unsigned short*)Dp)[(long)z * Dz + gr * ldd + gc] = f2bf(v);
        } else if constexpr (EPI == 2) {
          ((unsigned short*)Dp)[(long)z * Dz + gr * ldd + gc] = f2bf(v * scale);
        } else if constexpr (EPI == 3) {
          ((unsigned short*)Dp)[(long)z * Dz + gr * ldd + gc] = f2bf(v);
        } else {
          long o = (long)z * (512L * 1024L) + gr * 1024L + gc;
          ((float*)Dp)[o] = v + bias[gr] + residual[o];
        }
      }
    }
  }
}

extern "C" void kernel_launch(void* const* d_in, const int* in_sizes, int n_in,
                              void* d_out, int out_size, void* d_ws, size_t ws_size,
                              hipStream_t stream) {
  const float* x     = (const float*)d_in[0];
  const float* gamma = (const float*)d_in[1];
  const float* beta  = (const float*)d_in[2];
  const float* wq    = (const float*)d_in[3];
  const float* bq    = (const float*)d_in[4];
  const float* wk    = (const float*)d_in[5];
  const float* bk    = (const float*)d_in[6];
  const float* wv    = (const float*)d_in[7];
  const float* bv    = (const float*)d_in[8];
  const float* wo    = (const float*)d_in[9];
  const float* bo    = (const float*)d_in[10];
  float* out = (float*)d_out;

  char* ws = (char*)d_ws;
  unsigned short* ht   = (unsigned short*)(ws + 0);           // [16384,512] bf16
  unsigned short* qkt  = (unsigned short*)(ws + 16777216);    // [16384,1024] bf16 (q | k)
  unsigned short* vv   = (unsigned short*)(ws + 50331648);    // [512,16384] bf16
  unsigned short* ot   = (unsigned short*)(ws + 67108864);    // [16,1024,512] bf16
  unsigned short* S    = (unsigned short*)(ws + 83886080);    // [16,1024,1024] bf16 (P in-place)
  unsigned short* wqkb = (unsigned short*)(ws + 117440512);   // [1024,512] bf16
  unsigned short* wvb  = (unsigned short*)(ws + 119537664);   // [512,512] bf16
  unsigned short* wob  = (unsigned short*)(ws + 120061952);   // [512,512] bf16
  float* bqk           = (float*)(ws + 120586240);            // [1024] f32
  float* stats         = (float*)(ws + 120590336);            // [512,2] f32

  convert_w<<<1024, 256, 0, stream>>>(wq, wk, wv, wo, bq, bk, wqkb, wvb, wob, bqk);
  gn_stats<<<512, 256, 0, stream>>>(x, stats);
  gn_apply<<<dim3(16, 8, 16), 256, 0, stream>>>(x, stats, gamma, beta, ht);

  // G1: qkt[i, j] = sum_c ht[i,c] * wqk[j,c] + bqk[j]
  gemm_k<0><<<dim3(128, 8, 1), 256, 0, stream>>>(ht, 512, 0, wqkb, 512, 0,
                                                 qkt, 1024, 0, bqk, 0.f, 512, nullptr);
  // G2: vv[c, t] = sum_k wv[c,k] * ht[t,k] + bv[c]
  gemm_k<1><<<dim3(4, 128, 1), 256, 0, stream>>>(wvb, 512, 0, ht, 512, 0,
                                                 vv, 16384, 0, bv, 0.f, 512, nullptr);
  // G3: S[b,i,j] = bf16( scale * sum_c q[i,c] * k[j,c] )
  gemm_k<2><<<dim3(8, 8, 16), 256, 0, stream>>>(qkt, 1024, 1048576L, qkt + 512, 1024, 1048576L,
                                                S, 1024, 1048576L, nullptr,
                                                0.044194173824159216f, 512, nullptr);
  softmax_rows<<<16384, 256, 0, stream>>>(S);
  // G4: ot[b, i, c] = sum_j P[b,i,j] * vv[c, b*N+j]
  gemm_k<3><<<dim3(8, 4, 16), 256, 0, stream>>>(S, 1024, 1048576L,
                                                vv, 16384, 1024,
                                                ot, 512, 524288L, nullptr, 0.f, 1024, nullptr);
  // G5: out[b,o,n] = x + bo[o] + sum_c wo[o,c] * ot[b,n,c]
  gemm_k<4><<<dim3(4, 8, 16), 256, 0, stream>>>(wob, 512, 0, ot, 512, 524288L,
                                                out, 0, 0, bo, 0.f, 512, x);
}

// Round 3
// 158.705 us; speedup vs baseline: 1.3371x; 1.1867x over previous
//
#include <hip/hip_runtime.h>

typedef __attribute__((ext_vector_type(4))) float f32x4;
typedef __attribute__((ext_vector_type(8))) __bf16 bf16x8;
typedef __attribute__((ext_vector_type(4))) unsigned short us4;
typedef __attribute__((ext_vector_type(8))) unsigned short us8;

#define B_  16
#define C_  512
#define N_  1024
#define G_  32
#define GS  16

__device__ inline unsigned short f2bf(float f) {
  unsigned u = __builtin_bit_cast(unsigned, f);
  u += 0x7fffu + ((u >> 16) & 1u);
  return (unsigned short)(u >> 16);
}
__device__ inline float bf2f(unsigned short u) {
  unsigned x = (unsigned)u << 16;
  return __builtin_bit_cast(float, x);
}

#define GLOAD_LDS16(gp, lp) __builtin_amdgcn_global_load_lds( \
    (const __attribute__((address_space(1))) unsigned int*)(gp), \
    (__attribute__((address_space(3))) unsigned int*)(lp), 16, 0, 0)

// ---------------- GroupNorm ----------------
__global__ __launch_bounds__(256) void gn_stats(const float* __restrict__ x,
                                                float* __restrict__ stats) {
  int bg = blockIdx.x;                       // b*32+g
  const float* xp = x + (long)bg * (GS * N_);
  int tid = threadIdx.x;
  float s = 0.f, ss = 0.f;
  for (int i = tid * 4; i < GS * N_; i += 1024) {
    f32x4 v = *(const f32x4*)&xp[i];
    s += v.x + v.y + v.z + v.w;
    ss += v.x * v.x + v.y * v.y + v.z * v.z + v.w * v.w;
  }
  __shared__ float r1[256], r2[256];
  r1[tid] = s; r2[tid] = ss; __syncthreads();
  for (int off = 128; off > 0; off >>= 1) {
    if (tid < off) { r1[tid] += r1[tid + off]; r2[tid] += r2[tid + off]; }
    __syncthreads();
  }
  if (tid == 0) {
    float mean = r1[0] * (1.f / (GS * N_));
    float var  = r2[0] * (1.f / (GS * N_)) - mean * mean;
    stats[bg * 2]     = mean;
    stats[bg * 2 + 1] = rsqrtf(var + 1e-6f);
  }
}

// normalize + transpose: x[b,c,n] -> ht[(b*N+n)*C + c]  (bf16)
__global__ __launch_bounds__(256) void gn_apply(const float* __restrict__ x,
                                                const float* __restrict__ stats,
                                                const float* __restrict__ gamma,
                                                const float* __restrict__ beta,
                                                unsigned short* __restrict__ ht) {
  int b = blockIdx.z, ct = blockIdx.y, nt = blockIdx.x;
  int c0 = ct * 64, n0 = nt * 64;
  int tid = threadIdx.x;
  __shared__ unsigned short L[64 * 68];
  const float* xp = x + ((long)b * C_ + c0) * N_ + n0;
#pragma unroll
  for (int i = 0; i < 4; ++i) {
    int li = tid + i * 256;        // 0..1023
    int row = li >> 4;             // c offset 0..63
    int col4 = (li & 15) * 4;      // n offset
    f32x4 v = *(const f32x4*)&xp[(long)row * N_ + col4];
    int c = c0 + row;
    float mean = stats[(b * G_ + (c >> 4)) * 2];
    float rstd = stats[(b * G_ + (c >> 4)) * 2 + 1];
    float gm = gamma[c] * rstd;
    float bt = beta[c] - mean * gm;
    us4 o;
    o.x = f2bf(v.x * gm + bt); o.y = f2bf(v.y * gm + bt);
    o.z = f2bf(v.z * gm + bt); o.w = f2bf(v.w * gm + bt);
    *(us4*)&L[row * 68 + col4] = o;
  }
  __syncthreads();
#pragma unroll
  for (int i = 0; i < 2; ++i) {
    int s = tid + i * 256;         // 0..511
    int n = s >> 3;
    int cs = (s & 7) * 8;
    us8 o;
#pragma unroll
    for (int j = 0; j < 8; ++j) o[j] = L[(cs + j) * 68 + n];
    *(us8*)&ht[((long)b * N_ + n0 + n) * C_ + c0 + cs] = o;
  }
}

// ---------------- weight conversion ----------------
__global__ __launch_bounds__(256) void convert_w(const float* __restrict__ wq, const float* __restrict__ wk,
                                                 const float* __restrict__ wv, const float* __restrict__ wo,
                                                 const float* __restrict__ bq, const float* __restrict__ bk,
                                                 unsigned short* __restrict__ wqk, unsigned short* __restrict__ wvb,
                                                 unsigned short* __restrict__ wob, float* __restrict__ bqk) {
  int i = blockIdx.x * 256 + threadIdx.x;
  if (i < C_ * C_) {
    wqk[i]           = f2bf(wq[i]);
    wqk[C_ * C_ + i] = f2bf(wk[i]);
    wvb[i]           = f2bf(wv[i]);
    wob[i]           = f2bf(wo[i]);
  }
  if (i < C_) { bqk[i] = bq[i]; bqk[C_ + i] = bk[i]; }
}

// ---------------- MFMA GEMM, prefetch-pipelined:  D[i,j] = sum_k A[i,k]*B[j,k] ----------------
__device__ inline f32x4 mfma16(bf16x8 a, bf16x8 b, f32x4 c) {
  return __builtin_amdgcn_mfma_f32_16x16x32_bf16(a, b, c, 0, 0, 0);
}

// EPI: 0 = +bias[col], bf16 store      1 = +bias[row], bf16 store
//      4 = +bias[row] + residual, fp32 store to out[z, row, col]
//      5 = P=exp2(v*scale) bf16 store + per-row partial sums -> rs
//      6 = v * (1/sum(rs_row)), bf16 store
template<int EPI>
__global__ __launch_bounds__(256) void gemm_k(
    const unsigned short* __restrict__ A, long lda, long Az,
    const unsigned short* __restrict__ Bm, long ldb, long Bz,
    void* __restrict__ Dp, long ldd, long Dz,
    const float* __restrict__ bias, float scale, int K,
    const float* __restrict__ residual, float* __restrict__ rs) {
  const int z = blockIdx.z;
  const long row0 = (long)blockIdx.x * 128;
  const long col0 = (long)blockIdx.y * 128;
  const int tid  = threadIdx.x;
  const int lane = tid & 63;
  const int wave = tid >> 6;
  const int wr = (wave >> 1) * 64;
  const int wc = (wave & 1) * 64;
  const int lr = lane & 15;
  const int kh = (lane >> 4) * 8;

  __shared__ unsigned short As[2][128 * 32];
  __shared__ unsigned short Bs[2][128 * 32];
  __shared__ float dinv[128];

  if constexpr (EPI == 6) {
    if (tid < 128) {
      const float* rp = rs + ((long)z * 1024 + row0 + tid) * 16;
      float s = 0.f;
#pragma unroll
      for (int i = 0; i < 16; ++i) s += rp[i];
      dinv[tid] = 1.f / s;
    }
  }

  // staging coords: seg = wave*2 + s covers LDS rows seg*16..seg*16+15
  const int sr  = (lane >> 2);        // row within 16-row segment
  const int sk  = (lane & 3) * 8;     // k offset (shorts)
  const unsigned short* ga0 = A  + (long)z * Az + (row0 + wave * 32 + sr) * lda + sk;
  const unsigned short* gb0 = Bm + (long)z * Bz + (col0 + wave * 32 + sr) * ldb + sk;

  f32x4 acc[4][4];
#pragma unroll
  for (int m = 0; m < 4; ++m)
#pragma unroll
    for (int n = 0; n < 4; ++n) acc[m][n] = f32x4{0.f, 0.f, 0.f, 0.f};

  // prologue: stage tile 0 into buffer 0
  GLOAD_LDS16(ga0, &As[0][wave * 1024]);
  GLOAD_LDS16(ga0 + 16 * lda, &As[0][wave * 1024 + 512]);
  GLOAD_LDS16(gb0, &Bs[0][wave * 1024]);
  GLOAD_LDS16(gb0 + 16 * ldb, &Bs[0][wave * 1024 + 512]);
  __syncthreads();

  int cur = 0;
  for (int k0 = 0; k0 < K; k0 += 32) {
    // prefetch next tile into the other buffer (overlaps with this tile's compute)
    if (k0 + 32 < K) {
      const int nb = cur ^ 1;
      GLOAD_LDS16(ga0 + k0 + 32, &As[nb][wave * 1024]);
      GLOAD_LDS16(ga0 + 16 * lda + k0 + 32, &As[nb][wave * 1024 + 512]);
      GLOAD_LDS16(gb0 + k0 + 32, &Bs[nb][wave * 1024]);
      GLOAD_LDS16(gb0 + 16 * ldb + k0 + 32, &Bs[nb][wave * 1024 + 512]);
    }
    bf16x8 af[4], bfr[4];
#pragma unroll
    for (int m = 0; m < 4; ++m) af[m]  = *(const bf16x8*)&As[cur][(wr + m * 16 + lr) * 32 + kh];
#pragma unroll
    for (int n = 0; n < 4; ++n) bfr[n] = *(const bf16x8*)&Bs[cur][(wc + n * 16 + lr) * 32 + kh];
#pragma unroll
    for (int m = 0; m < 4; ++m)
#pragma unroll
      for (int n = 0; n < 4; ++n)
        acc[m][n] = mfma16(af[m], bfr[n], acc[m][n]);
    __syncthreads();
    cur ^= 1;
  }

  const int rb = (lane >> 4) * 4;
  if constexpr (EPI == 5) {
    const int jt = (int)blockIdx.y;
#pragma unroll
    for (int m = 0; m < 4; ++m) {
      float ps[4] = {0.f, 0.f, 0.f, 0.f};
#pragma unroll
      for (int n = 0; n < 4; ++n) {
#pragma unroll
        for (int r = 0; r < 4; ++r) {
          long gr = row0 + wr + m * 16 + rb + r;
          long gc = col0 + wc + n * 16 + lr;
          float e = exp2f(acc[m][n][r] * scale);   // scale includes log2e
          ((unsigned short*)Dp)[(long)z * Dz + gr * ldd + gc] = f2bf(e);
          ps[r] += e;
        }
      }
#pragma unroll
      for (int r = 0; r < 4; ++r) {
#pragma unroll
        for (int off = 1; off < 16; off <<= 1) ps[r] += __shfl_xor(ps[r], off);
      }
      if (lr == 0) {
#pragma unroll
        for (int r = 0; r < 4; ++r) {
          long gr = row0 + wr + m * 16 + rb + r;
          rs[((long)z * 1024 + gr) * 16 + jt * 2 + (wave & 1)] = ps[r];
        }
      }
    }
    return;
  }

#pragma unroll
  for (int m = 0; m < 4; ++m) {
#pragma unroll
    for (int n = 0; n < 4; ++n) {
#pragma unroll
      for (int r = 0; r < 4; ++r) {
        long gr = row0 + wr + m * 16 + rb + r;
        long gc = col0 + wc + n * 16 + lr;
        float v = acc[m][n][r];
        if constexpr (EPI == 0) {
          v += bias[gc];
          ((unsigned short*)Dp)[(long)z * Dz + gr * ldd + gc] = f2bf(v);
        } else if constexpr (EPI == 1) {
          v += bias[gr];
          ((unsigned short*)Dp)[(long)z * Dz + gr * ldd + gc] = f2bf(v);
        } else if constexpr (EPI == 6) {
          v *= dinv[(int)(gr - row0)];
          ((unsigned short*)Dp)[(long)z * Dz + gr * ldd + gc] = f2bf(v);
        } else {
          long o = (long)z * (512L * 1024L) + gr * 1024L + gc;
          ((float*)Dp)[o] = v + bias[gr] + residual[o];
        }
      }
    }
  }
}

extern "C" void kernel_launch(void* const* d_in, const int* in_sizes, int n_in,
                              void* d_out, int out_size, void* d_ws, size_t ws_size,
                              hipStream_t stream) {
  const float* x     = (const float*)d_in[0];
  const float* gamma = (const float*)d_in[1];
  const float* beta  = (const float*)d_in[2];
  const float* wq    = (const float*)d_in[3];
  const float* bq    = (const float*)d_in[4];
  const float* wk    = (const float*)d_in[5];
  const float* bk    = (const float*)d_in[6];
  const float* wv    = (const float*)d_in[7];
  const float* bv    = (const float*)d_in[8];
  const float* wo    = (const float*)d_in[9];
  const float* bo    = (const float*)d_in[10];
  float* out = (float*)d_out;

  char* ws = (char*)d_ws;
  unsigned short* ht   = (unsigned short*)(ws + 0);           // [16384,512] bf16
  unsigned short* qkt  = (unsigned short*)(ws + 16777216);    // [16384,1024] bf16 (q | k)
  unsigned short* vv   = (unsigned short*)(ws + 50331648);    // [512,16384] bf16
  unsigned short* ot   = (unsigned short*)(ws + 67108864);    // [16,1024,512] bf16
  unsigned short* S    = (unsigned short*)(ws + 83886080);    // [16,1024,1024] bf16 (P unnorm)
  unsigned short* wqkb = (unsigned short*)(ws + 117440512);   // [1024,512] bf16
  unsigned short* wvb  = (unsigned short*)(ws + 119537664);   // [512,512] bf16
  unsigned short* wob  = (unsigned short*)(ws + 120061952);   // [512,512] bf16
  float* bqk           = (float*)(ws + 120586240);            // [1024] f32
  float* stats         = (float*)(ws + 120590336);            // [512,2] f32
  float* rs            = (float*)(ws + 120594432);            // [16,1024,16] f32 partial rowsums

  convert_w<<<1024, 256, 0, stream>>>(wq, wk, wv, wo, bq, bk, wqkb, wvb, wob, bqk);
  gn_stats<<<512, 256, 0, stream>>>(x, stats);
  gn_apply<<<dim3(16, 8, 16), 256, 0, stream>>>(x, stats, gamma, beta, ht);

  // G1: qkt[i, j] = sum_c ht[i,c] * wqk[j,c] + bqk[j]
  gemm_k<0><<<dim3(128, 8, 1), 256, 0, stream>>>(ht, 512, 0, wqkb, 512, 0,
                                                 qkt, 1024, 0, bqk, 0.f, 512, nullptr, nullptr);
  // G2: vv[c, t] = sum_k wv[c,k] * ht[t,k] + bv[c]
  gemm_k<1><<<dim3(4, 128, 1), 256, 0, stream>>>(wvb, 512, 0, ht, 512, 0,
                                                 vv, 16384, 0, bv, 0.f, 512, nullptr, nullptr);
  // G3: S[b,i,j] = exp2( (sum_c q[i,c]*k[j,c]) * scale*log2e ), partial rowsums -> rs
  gemm_k<5><<<dim3(8, 8, 16), 256, 0, stream>>>(qkt, 1024, 1048576L, qkt + 512, 1024, 1048576L,
                                                S, 1024, 1048576L, nullptr,
                                                0.06375871416f, 512, nullptr, rs);
  // G4: ot[b, i, c] = (sum_j P[b,i,j] * vv[c, b*N+j]) / rowsum
  gemm_k<6><<<dim3(8, 4, 16), 256, 0, stream>>>(S, 1024, 1048576L,
                                                vv, 16384, 1024,
                                                ot, 512, 524288L, nullptr, 0.f, 1024, nullptr, rs);
  // G5: out[b,o,n] = x + bo[o] + sum_c wo[o,c] * ot[b,n,c]
  gemm_k<4><<<dim3(4, 8, 16), 256, 0, stream>>>(wob, 512, 0, ot, 512, 524288L,
                                                out, 0, 0, bo, 0.f, 512, x, nullptr);
}

// Round 4
// 152.799 us; speedup vs baseline: 1.3888x; 1.0387x over previous
//
#include <hip/hip_runtime.h>

typedef __attribute__((ext_vector_type(4))) float f32x4;
typedef __attribute__((ext_vector_type(8))) __bf16 bf16x8;
typedef __attribute__((ext_vector_type(4))) unsigned short us4;
typedef __attribute__((ext_vector_type(8))) unsigned short us8;

#define B_  16
#define C_  512
#define N_  1024
#define G_  32
#define GS  16

__device__ inline unsigned short f2bf(float f) {
  unsigned u = __builtin_bit_cast(unsigned, f);
  u += 0x7fffu + ((u >> 16) & 1u);
  return (unsigned short)(u >> 16);
}

#define GLOAD_LDS16(gp, lp) __builtin_amdgcn_global_load_lds( \
    (const __attribute__((address_space(1))) unsigned int*)(gp), \
    (__attribute__((address_space(3))) unsigned int*)(lp), 16, 0, 0)

// ---------------- GroupNorm ----------------
__global__ __launch_bounds__(256) void gn_stats(const float* __restrict__ x,
                                                float* __restrict__ stats) {
  int bg = blockIdx.x;                       // b*32+g
  const float* xp = x + (long)bg * (GS * N_);
  int tid = threadIdx.x;
  float s = 0.f, ss = 0.f;
  for (int i = tid * 4; i < GS * N_; i += 1024) {
    f32x4 v = *(const f32x4*)&xp[i];
    s += v.x + v.y + v.z + v.w;
    ss += v.x * v.x + v.y * v.y + v.z * v.z + v.w * v.w;
  }
  __shared__ float r1[256], r2[256];
  r1[tid] = s; r2[tid] = ss; __syncthreads();
  for (int off = 128; off > 0; off >>= 1) {
    if (tid < off) { r1[tid] += r1[tid + off]; r2[tid] += r2[tid + off]; }
    __syncthreads();
  }
  if (tid == 0) {
    float mean = r1[0] * (1.f / (GS * N_));
    float var  = r2[0] * (1.f / (GS * N_)) - mean * mean;
    stats[bg * 2]     = mean;
    stats[bg * 2 + 1] = rsqrtf(var + 1e-6f);
  }
}

// normalize + transpose: x[b,c,n] -> ht[(b*N+n)*C + c]  (bf16)
__global__ __launch_bounds__(256) void gn_apply(const float* __restrict__ x,
                                                const float* __restrict__ stats,
                                                const float* __restrict__ gamma,
                                                const float* __restrict__ beta,
                                                unsigned short* __restrict__ ht) {
  int b = blockIdx.z, ct = blockIdx.y, nt = blockIdx.x;
  int c0 = ct * 64, n0 = nt * 64;
  int tid = threadIdx.x;
  __shared__ unsigned short L[64 * 68];
  const float* xp = x + ((long)b * C_ + c0) * N_ + n0;
#pragma unroll
  for (int i = 0; i < 4; ++i) {
    int li = tid + i * 256;        // 0..1023
    int row = li >> 4;             // c offset 0..63
    int col4 = (li & 15) * 4;      // n offset
    f32x4 v = *(const f32x4*)&xp[(long)row * N_ + col4];
    int c = c0 + row;
    float mean = stats[(b * G_ + (c >> 4)) * 2];
    float rstd = stats[(b * G_ + (c >> 4)) * 2 + 1];
    float gm = gamma[c] * rstd;
    float bt = beta[c] - mean * gm;
    us4 o;
    o.x = f2bf(v.x * gm + bt); o.y = f2bf(v.y * gm + bt);
    o.z = f2bf(v.z * gm + bt); o.w = f2bf(v.w * gm + bt);
    *(us4*)&L[row * 68 + col4] = o;
  }
  __syncthreads();
#pragma unroll
  for (int i = 0; i < 2; ++i) {
    int s = tid + i * 256;         // 0..511
    int n = s >> 3;
    int cs = (s & 7) * 8;
    us8 o;
#pragma unroll
    for (int j = 0; j < 8; ++j) o[j] = L[(cs + j) * 68 + n];
    *(us8*)&ht[((long)b * N_ + n0 + n) * C_ + c0 + cs] = o;
  }
}

// ---------------- weight conversion ----------------
__global__ __launch_bounds__(256) void convert_w(const float* __restrict__ wq, const float* __restrict__ wk,
                                                 const float* __restrict__ wv, const float* __restrict__ wo,
                                                 const float* __restrict__ bq, const float* __restrict__ bk,
                                                 unsigned short* __restrict__ wqk, unsigned short* __restrict__ wvb,
                                                 unsigned short* __restrict__ wob, float* __restrict__ bqk) {
  int i = blockIdx.x * 256 + threadIdx.x;
  if (i < C_ * C_) {
    wqk[i]           = f2bf(wq[i]);
    wqk[C_ * C_ + i] = f2bf(wk[i]);
    wvb[i]           = f2bf(wv[i]);
    wob[i]           = f2bf(wo[i]);
  }
  if (i < C_) { bqk[i] = bq[i]; bqk[C_ + i] = bk[i]; }
}

// ---------------- 256x(256|128) 8-wave MFMA GEMM, counted-vmcnt pipeline ----------------
// D[i,j] = sum_k A[i,k]*B[j,k]; both operands K-contiguous rows.
__device__ inline f32x4 mfma16(bf16x8 a, bf16x8 b, f32x4 c) {
  return __builtin_amdgcn_mfma_f32_16x16x32_bf16(a, b, c, 0, 0, 0);
}

__device__ inline int swz(int b) { return b ^ (((b >> 9) & 1) << 5); }

// EPI: 0 = +bias[col], bf16    1 = +bias[row], bf16
//      4 = +bias[row]+residual, f32 to out[z, row, col]
//      5 = exp2(v*scale) bf16 + per-row partial sums -> rs
//      6 = v * dinv(row), bf16
template<int NREP, int EPI>
__global__ __launch_bounds__(512, 2) void gemm256(
    const unsigned short* __restrict__ A, long lda, long Az,
    const unsigned short* __restrict__ Bm, long ldb, long Bz,
    void* __restrict__ Dp, long ldd, long Dz,
    const float* __restrict__ bias, float scale, int K,
    const float* __restrict__ residual, float* __restrict__ rs) {
  constexpr int BN = NREP * 64;
  const int z = blockIdx.z;
  const long row0 = (long)blockIdx.x * 256;
  const long col0 = (long)blockIdx.y * BN;
  const int tid  = threadIdx.x;
  const int lane = tid & 63;
  const int wave = tid >> 6;
  const int wm = wave >> 2;           // 0..1
  const int wn = wave & 3;            // 0..3
  const int lr = lane & 15;
  const int khb = (lane >> 4) * 16;   // byte offset of 16B chunk within 128B row

  __shared__ unsigned short Abuf[2][16384];      // [256][64] per buf
  __shared__ unsigned short Bbuf[2][BN * 64];    // [BN][64] per buf
  __shared__ float dinv_s[256];

  const unsigned short* Ab = A  + (long)z * Az;
  const unsigned short* Bb = Bm + (long)z * Bz;

  if constexpr (EPI == 6) {
    if (tid < 256) {
      const float* rp = rs + ((long)z * 1024 + row0 + tid) * 16;
      float s = 0.f;
#pragma unroll
      for (int i = 0; i < 16; ++i) s += rp[i];
      dinv_s[tid] = 1.f / s;
    }
    asm volatile("s_waitcnt lgkmcnt(0)" ::: "memory");
  }

  // staging source pointers (inverse-swizzled: data for physical LDS byte D comes
  // from logical byte L = swz(D); XOR is an involution, reads apply the same swz)
  const unsigned short* gA[4];
#pragma unroll
  for (int r = 0; r < 4; ++r) {
    int L = swz(r * 8192 + tid * 16);
    gA[r] = Ab + (row0 + (L >> 7)) * lda + ((L & 127) >> 1);
  }
  const unsigned short* gB[NREP];
#pragma unroll
  for (int r = 0; r < NREP; ++r) {
    int L = swz(r * 8192 + tid * 16);
    gB[r] = Bb + (col0 + (L >> 7)) * ldb + ((L & 127) >> 1);
  }

  f32x4 acc[8][NREP];
#pragma unroll
  for (int m = 0; m < 8; ++m)
#pragma unroll
    for (int n = 0; n < NREP; ++n) acc[m][n] = f32x4{0.f, 0.f, 0.f, 0.f};

  const int NT = K >> 6;
  // prologue: stage tile 0 into buf 0
#pragma unroll
  for (int r = 0; r < 4; ++r)    GLOAD_LDS16(gA[r], &Abuf[0][r * 4096 + wave * 512]);
#pragma unroll
  for (int r = 0; r < NREP; ++r) GLOAD_LDS16(gB[r], &Bbuf[0][r * 4096 + wave * 512]);

  for (int t = 0; t < NT; ++t) {
    int tn = t + 1; if (tn == NT) tn = 0;          // wrap keeps vmcnt math uniform
    const long ko = (long)tn << 6;
    const int nb = (t + 1) & 1;
#pragma unroll
    for (int r = 0; r < 4; ++r)    GLOAD_LDS16(gA[r] + ko, &Abuf[nb][r * 4096 + wave * 512]);
#pragma unroll
    for (int r = 0; r < NREP; ++r) GLOAD_LDS16(gB[r] + ko, &Bbuf[nb][r * 4096 + wave * 512]);
    // counted wait: current tile's (oldest) loads landed; next tile's stay in flight
    if constexpr (NREP == 4) asm volatile("s_waitcnt vmcnt(8)" ::: "memory");
    else                     asm volatile("s_waitcnt vmcnt(6)" ::: "memory");
    __builtin_amdgcn_s_barrier();
    __builtin_amdgcn_sched_barrier(0);
    const unsigned short* Al = Abuf[t & 1];
    const unsigned short* Bl = Bbuf[t & 1];
#pragma unroll
    for (int kk = 0; kk < 2; ++kk) {
      bf16x8 af[8], bfr[NREP];
#pragma unroll
      for (int m = 0; m < 8; ++m) {
        int Pb = swz((wm * 128 + m * 16 + lr) * 128 + kk * 64 + khb);
        af[m] = *(const bf16x8*)((const char*)Al + Pb);
      }
#pragma unroll
      for (int n = 0; n < NREP; ++n) {
        int Pb = swz((wn * NREP * 16 + n * 16 + lr) * 128 + kk * 64 + khb);
        bfr[n] = *(const bf16x8*)((const char*)Bl + Pb);
      }
      __builtin_amdgcn_s_setprio(1);
#pragma unroll
      for (int m = 0; m < 8; ++m)
#pragma unroll
        for (int n = 0; n < NREP; ++n)
          acc[m][n] = mfma16(af[m], bfr[n], acc[m][n]);
      __builtin_amdgcn_s_setprio(0);
    }
    __builtin_amdgcn_sched_barrier(0);
    __builtin_amdgcn_s_barrier();
    __builtin_amdgcn_sched_barrier(0);
  }
  asm volatile("s_waitcnt vmcnt(0)" ::: "memory");   // drain wrapped stage before exit

  const int rb = (lane >> 4) * 4;
  if constexpr (EPI == 5) {
    const int jt = blockIdx.y;
#pragma unroll
    for (int m = 0; m < 8; ++m) {
      float ps[4] = {0.f, 0.f, 0.f, 0.f};
#pragma unroll
      for (int n = 0; n < NREP; ++n) {
#pragma unroll
        for (int r = 0; r < 4; ++r) {
          long gr = row0 + wm * 128 + m * 16 + rb + r;
          long gc = col0 + wn * NREP * 16 + n * 16 + lr;
          float e = exp2f(acc[m][n][r] * scale);   // scale includes log2e
          ((unsigned short*)Dp)[(long)z * Dz + gr * ldd + gc] = f2bf(e);
          ps[r] += e;
        }
      }
#pragma unroll
      for (int r = 0; r < 4; ++r) {
        ps[r] += __shfl_xor(ps[r], 1);
        ps[r] += __shfl_xor(ps[r], 2);
        ps[r] += __shfl_xor(ps[r], 4);
        ps[r] += __shfl_xor(ps[r], 8);
      }
      if (lr == 0) {
#pragma unroll
        for (int r = 0; r < 4; ++r) {
          long gr = row0 + wm * 128 + m * 16 + rb + r;
          rs[((long)z * 1024 + gr) * 16 + jt * 4 + wn] = ps[r];
        }
      }
    }
    return;
  }

#pragma unroll
  for (int m = 0; m < 8; ++m) {
#pragma unroll
    for (int n = 0; n < NREP; ++n) {
#pragma unroll
      for (int r = 0; r < 4; ++r) {
        long gr = row0 + wm * 128 + m * 16 + rb + r;
        long gc = col0 + wn * NREP * 16 + n * 16 + lr;
        float v = acc[m][n][r];
        if constexpr (EPI == 0) {
          v += bias[gc];
          ((unsigned short*)Dp)[(long)z * Dz + gr * ldd + gc] = f2bf(v);
        } else if constexpr (EPI == 1) {
          v += bias[gr];
          ((unsigned short*)Dp)[(long)z * Dz + gr * ldd + gc] = f2bf(v);
        } else if constexpr (EPI == 6) {
          v *= dinv_s[(int)(wm * 128 + m * 16 + rb + r)];
          ((unsigned short*)Dp)[(long)z * Dz + gr * ldd + gc] = f2bf(v);
        } else {
          long o = (long)z * (512L * 1024L) + gr * 1024L + gc;
          ((float*)Dp)[o] = v + bias[gr] + residual[o];
        }
      }
    }
  }
}

extern "C" void kernel_launch(void* const* d_in, const int* in_sizes, int n_in,
                              void* d_out, int out_size, void* d_ws, size_t ws_size,
                              hipStream_t stream) {
  const float* x     = (const float*)d_in[0];
  const float* gamma = (const float*)d_in[1];
  const float* beta  = (const float*)d_in[2];
  const float* wq    = (const float*)d_in[3];
  const float* bq    = (const float*)d_in[4];
  const float* wk    = (const float*)d_in[5];
  const float* bk    = (const float*)d_in[6];
  const float* wv    = (const float*)d_in[7];
  const float* bv    = (const float*)d_in[8];
  const float* wo    = (const float*)d_in[9];
  const float* bo    = (const float*)d_in[10];
  float* out = (float*)d_out;

  char* ws = (char*)d_ws;
  unsigned short* ht   = (unsigned short*)(ws + 0);           // [16384,512] bf16
  unsigned short* qkt  = (unsigned short*)(ws + 16777216);    // [16384,1024] bf16 (q | k)
  unsigned short* vv   = (unsigned short*)(ws + 50331648);    // [512,16384] bf16
  unsigned short* ot   = (unsigned short*)(ws + 67108864);    // [16,1024,512] bf16
  unsigned short* S    = (unsigned short*)(ws + 83886080);    // [16,1024,1024] bf16 (P unnorm)
  unsigned short* wqkb = (unsigned short*)(ws + 117440512);   // [1024,512] bf16
  unsigned short* wvb  = (unsigned short*)(ws + 119537664);   // [512,512] bf16
  unsigned short* wob  = (unsigned short*)(ws + 120061952);   // [512,512] bf16
  float* bqk           = (float*)(ws + 120586240);            // [1024] f32
  float* stats         = (float*)(ws + 120590336);            // [512,2] f32
  float* rs            = (float*)(ws + 120594432);            // [16,1024,16] f32 partial rowsums

  convert_w<<<1024, 256, 0, stream>>>(wq, wk, wv, wo, bq, bk, wqkb, wvb, wob, bqk);
  gn_stats<<<512, 256, 0, stream>>>(x, stats);
  gn_apply<<<dim3(16, 8, 16), 256, 0, stream>>>(x, stats, gamma, beta, ht);

  // G1: qkt[i, j] = sum_c ht[i,c] * wqk[j,c] + bqk[j]      (64x4 = 256 blocks)
  gemm256<4, 0><<<dim3(64, 4, 1), 512, 0, stream>>>(ht, 512, 0, wqkb, 512, 0,
                                                    qkt, 1024, 0, bqk, 0.f, 512, nullptr, nullptr);
  // G2: vv[c, t] = sum_k wv[c,k] * ht[t,k] + bv[c]         (2x128 = 256 blocks)
  gemm256<2, 1><<<dim3(2, 128, 1), 512, 0, stream>>>(wvb, 512, 0, ht, 512, 0,
                                                     vv, 16384, 0, bv, 0.f, 512, nullptr, nullptr);
  // G3: S[b,i,j] = exp2(scale' * sum_c q[i,c]*k[j,c]), partial rowsums -> rs  (4x4x16)
  gemm256<4, 5><<<dim3(4, 4, 16), 512, 0, stream>>>(qkt, 1024, 1048576L, qkt + 512, 1024, 1048576L,
                                                    S, 1024, 1048576L, nullptr,
                                                    0.06375871416f, 512, nullptr, rs);
  // G4: ot[b, i, c] = (sum_j P[b,i,j] * vv[c, b*N+j]) / rowsum   (4x4x16)
  gemm256<2, 6><<<dim3(4, 4, 16), 512, 0, stream>>>(S, 1024, 1048576L,
                                                    vv, 16384, 1024,
                                                    ot, 512, 524288L, nullptr, 0.f, 1024, nullptr, rs);
  // G5: out[b,o,n] = x + bo[o] + sum_c wo[o,c] * ot[b,n,c]       (2x8x16)
  gemm256<2, 4><<<dim3(2, 8, 16), 512, 0, stream>>>(wob, 512, 0, ot, 512, 524288L,
                                                    out, 0, 0, bo, 0.f, 512, x, nullptr);
}